// Round 4
// baseline (260.229 us; speedup 1.0000x reference)
//
#include <hip/hip_runtime.h>
#include <math.h>
#include <float.h>

typedef __attribute__((ext_vector_type(4))) float f32x4;
typedef __attribute__((ext_vector_type(8))) __bf16 bf16x8;
typedef __attribute__((ext_vector_type(4))) __bf16 bf16x4;

#define NEG_TOPK 10
#define BROW 256      // batch rows, full per block
#define MT 64         // output cols per block
#define BK 64         // K-step
#define SIMSTR 72     // ushort stride for sims (144 B rows, 16B-aligned)
#define BUF 40960     // bytes per staging buffer: A 32 KB + B 8 KB

// Branchless static-index top-k insert (sorted descending); pure VGPRs.
__device__ __forceinline__ void topk_ins(float (&top)[NEG_TOPK], float v) {
    #pragma unroll
    for (int q = NEG_TOPK - 1; q >= 1; --q)
        top[q] = fmaxf(fminf(v, top[q - 1]), top[q]);
    top[0] = fmaxf(top[0], v);
}

__device__ __forceinline__ bf16x4 cvt4(float4 v) {
    bf16x4 r;
    r[0] = (__bf16)v.x; r[1] = (__bf16)v.y;
    r[2] = (__bf16)v.z; r[3] = (__bf16)v.w;
    return r;
}

// Pass 1: bf16 MFMA GEMM, 256x64 tile, 8 waves (4x2) of 64x32 wave-tiles,
// double-buffered LDS with ONE barrier per K-step; fused epilogue produces
// per-(row, 64-col chunk) top-10 partials + positive-loss partials.
__global__ __launch_bounds__(512, 2) void cl_pass1(
    const float* __restrict__ A,    // [256, D] inputs_col fp32
    const float* __restrict__ Bm,   // [M, D]  inputs_row fp32
    const int* __restrict__ tcol,   // [256]
    const int* __restrict__ trow,   // [M]
    float* __restrict__ part_topk,  // [256, nch, 10]   nch = gridDim.x
    float* __restrict__ pos_part,   // [256, nch]
    int D)
{
    __shared__ char smem[2 * BUF];  // 81920 B -> 2 blocks/CU = 160 KB exactly

    const int mb = blockIdx.x;
    const int j0 = mb * MT;
    const int t  = threadIdx.x;
    const int wave = t >> 6, lane = t & 63;
    const int wr = wave >> 1, wc = wave & 1;   // 4x2 waves; wave tile 64x32
    const int lrow = lane & 15, lk = lane >> 4;

    const float4* A4 = (const float4*)A;
    const float4* B4 = (const float4*)Bm;
    const int ldq = D >> 2;          // float4 per row (128)
    const int NSTEP = D / BK;        // 8

    // per-thread staging slices (constant across steps)
    const int ra = t >> 4;                 // A rows t>>4 + 32*s
    const int k4 = t & 15;                 // float4 index within 64-k chunk
    const int rb = t >> 4;                 // B rows t>>4 + 32*s (s<2)

    f32x4 acc[4][2];
    #pragma unroll
    for (int m = 0; m < 4; ++m)
        #pragma unroll
        for (int n = 0; n < 2; ++n)
            acc[m][n] = (f32x4){0.f, 0.f, 0.f, 0.f};

    float4 ar[8];   // A: 256x64 fp32 = 4096 f4 / 512 thr
    float4 br[2];   // B:  64x64 fp32 = 1024 f4 / 512 thr

    // ---- prologue: load + stage step 0 into buf0
    #pragma unroll
    for (int s = 0; s < 8; ++s) ar[s] = A4[(ra + 32 * s) * ldq + k4];
    #pragma unroll
    for (int s = 0; s < 2; ++s) br[s] = B4[(size_t)(j0 + rb + 32 * s) * ldq + k4];
    {
        char* Ab = smem;            // buf0 A
        char* Bb = smem + 32768;    // buf0 B
        #pragma unroll
        for (int s = 0; s < 8; ++s) {
            int r = ra + 32 * s;
            *(bf16x4*)(Ab + r * 128 + ((k4 * 8) ^ ((r & 7) << 4))) = cvt4(ar[s]);
        }
        #pragma unroll
        for (int s = 0; s < 2; ++s) {
            int r = rb + 32 * s;
            *(bf16x4*)(Bb + r * 128 + ((k4 * 8) ^ ((r & 7) << 4))) = cvt4(br[s]);
        }
    }

    const int swz = (lrow & 7) << 4;

    for (int step = 0; step < NSTEP; ++step) {
        const int cur = step & 1;
        __syncthreads();   // buf[cur] staged & visible; buf[cur^1] fully consumed

        // issue next tile's global loads (vm-wait lands after compute)
        if (step + 1 < NSTEP) {
            const int kq = (step + 1) * (BK / 4);
            #pragma unroll
            for (int s = 0; s < 8; ++s) ar[s] = A4[(ra + 32 * s) * ldq + kq + k4];
            #pragma unroll
            for (int s = 0; s < 2; ++s)
                br[s] = B4[(size_t)(j0 + rb + 32 * s) * ldq + kq + k4];
        }

        // compute from buf[cur]
        {
            const char* Ab = smem + cur * BUF;
            const char* Bb = Ab + 32768;
            #pragma unroll
            for (int ks = 0; ks < 2; ++ks) {
                bf16x8 af[4], bfr[2];
                const int kb = ks * 64 + lk * 16;
                #pragma unroll
                for (int m = 0; m < 4; ++m) {
                    int row = wr * 64 + m * 16 + lrow;
                    af[m] = *(const bf16x8*)(Ab + row * 128 + (kb ^ swz));
                }
                #pragma unroll
                for (int n = 0; n < 2; ++n) {
                    int row = wc * 32 + n * 16 + lrow;
                    bfr[n] = *(const bf16x8*)(Bb + row * 128 + (kb ^ swz));
                }
                #pragma unroll
                for (int m = 0; m < 4; ++m)
                    #pragma unroll
                    for (int n = 0; n < 2; ++n)
                        acc[m][n] = __builtin_amdgcn_mfma_f32_16x16x32_bf16(
                            af[m], bfr[n], acc[m][n], 0, 0, 0);
            }
        }

        // stage next tile into buf[cur^1] (no barrier needed: other waves only
        // read buf[cur]; buf[cur^1] was drained before the barrier above)
        if (step + 1 < NSTEP) {
            char* Ab = smem + (cur ^ 1) * BUF;
            char* Bb = Ab + 32768;
            #pragma unroll
            for (int s = 0; s < 8; ++s) {
                int r = ra + 32 * s;
                *(bf16x4*)(Ab + r * 128 + ((k4 * 8) ^ ((r & 7) << 4))) = cvt4(ar[s]);
            }
            #pragma unroll
            for (int s = 0; s < 2; ++s) {
                int r = rb + 32 * s;
                *(bf16x4*)(Bb + r * 128 + ((k4 * 8) ^ ((r & 7) << 4))) = cvt4(br[s]);
            }
        }
    }

    // ---- epilogue: sims (bf16, [256][72]) into buf0 region (safe: all waves
    // past step-7 barrier read only buf1)
    unsigned short* simsb = (unsigned short*)smem;
    #pragma unroll
    for (int m = 0; m < 4; ++m)
        #pragma unroll
        for (int n = 0; n < 2; ++n)
            #pragma unroll
            for (int r = 0; r < 4; ++r) {
                int row = wr * 64 + m * 16 + lk * 4 + r;
                int col = wc * 32 + n * 16 + lrow;
                __bf16 b = (__bf16)acc[m][n][r];
                simsb[row * SIMSTR + col] = *(unsigned short*)&b;
            }
    __syncthreads();

    // fused scan: 2 threads per row, 32 cols each; labels straight from global
    {
        const int row = t >> 1, half = t & 1;
        const int myc = tcol[row];
        const int4* lab4 = (const int4*)(trow + j0 + half * 32);
        float top[NEG_TOPK];
        #pragma unroll
        for (int q = 0; q < NEG_TOPK; ++q) top[q] = -INFINITY;
        float pos = 0.f;
        #pragma unroll
        for (int j = 0; j < 4; ++j) {
            bf16x8 v8 = *(const bf16x8*)(&simsb[row * SIMSTR + half * 32 + j * 8]);
            int4 l1 = lab4[2 * j], l2 = lab4[2 * j + 1];
            int lab[8] = {l1.x, l1.y, l1.z, l1.w, l2.x, l2.y, l2.z, l2.w};
            #pragma unroll
            for (int e = 0; e < 8; ++e) {
                float s = (float)v8[e];
                bool same = (lab[e] == myc);
                pos += (same && s < 0.99999f) ? (1.f - s) : 0.f;
                topk_ins(top, same ? -INFINITY : s);
            }
        }
        // pair-merge via buf1 region (free now)
        float* mtop = (float*)(smem + BUF);            // [512][10]
        float* mpos = (float*)(smem + BUF + 20480);    // [512]
        #pragma unroll
        for (int q = 0; q < NEG_TOPK; ++q) mtop[t * NEG_TOPK + q] = top[q];
        mpos[t] = pos;
        __syncthreads();
        if (half == 0) {
            const float* ot = &mtop[(t + 1) * NEG_TOPK];
            #pragma unroll
            for (int q = 0; q < NEG_TOPK; ++q) topk_ins(top, ot[q]);
            float post = pos + mpos[t + 1];
            float* dst = part_topk + ((size_t)row * gridDim.x + mb) * NEG_TOPK;
            #pragma unroll
            for (int q = 0; q < NEG_TOPK; ++q) dst[q] = top[q];
            pos_part[(size_t)row * gridDim.x + mb] = post;
        }
    }
}

// Pass 2: one block per row. Merge nch*10 candidates -> top-10, sum finite;
// reduce pos partials; row_tot[i] = pos + neg.
__global__ __launch_bounds__(256) void cl_pass2(
    const float* __restrict__ part_topk,
    const float* __restrict__ pos_part,
    float* __restrict__ row_tot,
    int nch)
{
    const int i = blockIdx.x;
    const int t = threadIdx.x;
    __shared__ float stop[256][NEG_TOPK];
    __shared__ float stop2[32][NEG_TOPK];
    __shared__ float red[256];

    const int n = nch * NEG_TOPK;
    const float* src = part_topk + (size_t)i * n;
    float top[NEG_TOPK];
    #pragma unroll
    for (int q = 0; q < NEG_TOPK; ++q) top[q] = -INFINITY;
    for (int idx = t; idx < n; idx += 256) topk_ins(top, src[idx]);
    #pragma unroll
    for (int q = 0; q < NEG_TOPK; ++q) stop[t][q] = top[q];

    float pos = 0.0f;
    const float* psrc = pos_part + (size_t)i * nch;
    for (int idx = t; idx < nch; idx += 256) pos += psrc[idx];
    red[t] = pos;
    __syncthreads();

    for (int s2 = 128; s2 >= 1; s2 >>= 1) {
        if (t < s2) red[t] += red[t + s2];
        __syncthreads();
    }

    if (t < 32) {
        float m[NEG_TOPK];
        #pragma unroll
        for (int q = 0; q < NEG_TOPK; ++q) m[q] = -INFINITY;
        for (int l = 0; l < 8; ++l)
            #pragma unroll
            for (int q = 0; q < NEG_TOPK; ++q) topk_ins(m, stop[t * 8 + l][q]);
        #pragma unroll
        for (int q = 0; q < NEG_TOPK; ++q) stop2[t][q] = m[q];
    }
    __syncthreads();

    if (t == 0) {
        float m[NEG_TOPK];
        #pragma unroll
        for (int q = 0; q < NEG_TOPK; ++q) m[q] = -INFINITY;
        for (int l = 0; l < 32; ++l)
            #pragma unroll
            for (int q = 0; q < NEG_TOPK; ++q) topk_ins(m, stop2[l][q]);
        float neg = 0.0f;
        #pragma unroll
        for (int q = 0; q < NEG_TOPK; ++q)
            if (isfinite(m[q])) neg += m[q];
        row_tot[i] = neg + red[0];
    }
}

// Pass 3: mean over rows.
__global__ __launch_bounds__(256) void cl_pass3(
    const float* __restrict__ row_tot, float* __restrict__ out, int Bn)
{
    __shared__ float red[256];
    const int t = threadIdx.x;
    float v = 0.0f;
    for (int idx = t; idx < Bn; idx += 256) v += row_tot[idx];
    red[t] = v;
    __syncthreads();
    for (int s2 = 128; s2 >= 1; s2 >>= 1) {
        if (t < s2) red[t] += red[t + s2];
        __syncthreads();
    }
    if (t == 0) out[0] = red[0] / (float)Bn;
}

extern "C" void kernel_launch(void* const* d_in, const int* in_sizes, int n_in,
                              void* d_out, int out_size, void* d_ws, size_t ws_size,
                              hipStream_t stream)
{
    const float* A    = (const float*)d_in[0];  // inputs_col [B,D]
    const int*   tcol = (const int*)d_in[1];    // targets_col [B]
    const float* Bm   = (const float*)d_in[2];  // inputs_row [M,D]
    const int*   trow = (const int*)d_in[3];    // target_row [M]
    float* out = (float*)d_out;

    const int Bn = in_sizes[1];          // 256
    const int M  = in_sizes[3];          // 65536
    const int D  = in_sizes[0] / Bn;     // 512
    const int numMB = M / MT;            // 1024 blocks = chunks
    const int nch = numMB;

    float* part_topk = (float*)d_ws;                              // B*nch*10
    float* pos_part  = part_topk + (size_t)Bn * nch * NEG_TOPK;   // B*nch
    float* row_tot   = pos_part + (size_t)Bn * nch;               // B

    cl_pass1<<<numMB, 512, 0, stream>>>(A, Bm, tcol, trow, part_topk, pos_part, D);
    cl_pass2<<<Bn, 256, 0, stream>>>(part_topk, pos_part, row_tot, nch);
    cl_pass3<<<1, 256, 0, stream>>>(row_tot, out, Bn);
}